// Round 19
// baseline (4806.891 us; speedup 1.0000x reference)
//
#include <hip/hip_runtime.h>
#include <hip/hip_fp16.h>
#include <math.h>

constexpr int N_NODES = 4096;
constexpr int N_EDGES = 65536;
constexpr int D_INF   = 64;
constexpr int H       = 128;
constexpr int T       = 8;
constexpr int B       = 8;
constexpr int M       = B * N_NODES;

typedef __attribute__((ext_vector_type(8))) short bf16x8;
typedef __attribute__((ext_vector_type(4))) float f32x4;
typedef __attribute__((ext_vector_type(8))) _Float16 f16x8;

__device__ inline unsigned short f2bf(float x) {
  unsigned int u = __float_as_uint(x);
  unsigned int r = (u + 0x7fffu + ((u >> 16) & 1u)) >> 16;
  return (unsigned short)r;
}
__device__ inline float bf2f(unsigned short b) {
  return __uint_as_float((unsigned int)b << 16);
}
// LDS bank swizzle: XOR short-index bits 7-9 into bits 3-5 (bank bits).
__device__ __forceinline__ int swz(int s) { return s ^ (((s >> 7) & 7) << 3); }

// ---------------- CSR build ----------------

__global__ void k_count(const int* __restrict__ dst, int* __restrict__ cnt) {
  int e = blockIdx.x * blockDim.x + threadIdx.x;
  if (e < N_EDGES) atomicAdd(&cnt[dst[e]], 1);
}

__global__ void k_dinv(const int* __restrict__ cnt, float* __restrict__ dinv) {
  int n = blockIdx.x * blockDim.x + threadIdx.x;
  if (n < N_NODES) dinv[n] = 1.0f / sqrtf((float)cnt[n] + 2.0f);
}

__global__ void k_scan(const int* __restrict__ cnt, int* __restrict__ rowptr) {
  __shared__ int sums[1024];
  int t = threadIdx.x;
  int v0 = cnt[4*t+0], v1 = cnt[4*t+1], v2 = cnt[4*t+2], v3 = cnt[4*t+3];
  int s0 = v0, s1 = s0 + v1, s2 = s1 + v2, s3 = s2 + v3;
  sums[t] = s3;
  __syncthreads();
  for (int off = 1; off < 1024; off <<= 1) {
    int x = (t >= off) ? sums[t - off] : 0;
    __syncthreads();
    sums[t] += x;
    __syncthreads();
  }
  int base = (t > 0) ? sums[t - 1] : 0;
  if (t == 0) rowptr[0] = 0;
  rowptr[4*t+1] = base + s0;
  rowptr[4*t+2] = base + s1;
  rowptr[4*t+3] = base + s2;
  rowptr[4*t+4] = base + s3;
}

__global__ void k_fill(const int* __restrict__ src, const int* __restrict__ dst,
                       const float* __restrict__ dinv, const int* __restrict__ rowptr,
                       int* __restrict__ fill, int2* __restrict__ eg) {
  int e = blockIdx.x * blockDim.x + threadIdx.x;
  if (e >= N_EDGES) return;
  int s = src[e], d = dst[e];
  int p = rowptr[d] + atomicAdd(&fill[d], 1);
  eg[p] = make_int2(s, __float_as_int(dinv[s] * dinv[d]));
}

// ---- degree counting sort (work balance only; output unchanged) ----
__global__ void k_hist(const int* __restrict__ cnt, int* __restrict__ hist) {
  int n = blockIdx.x * blockDim.x + threadIdx.x;
  if (n < N_NODES) atomicAdd(&hist[min(cnt[n], 127)], 1);
}

__global__ void k_hscan(const int* __restrict__ hist, int* __restrict__ hbase) {
  __shared__ int sh[128];
  int t = threadIdx.x;
  sh[t] = hist[t];
  __syncthreads();
  for (int off = 1; off < 128; off <<= 1) {
    int x = (t >= off) ? sh[t - off] : 0;
    __syncthreads();
    sh[t] += x;
    __syncthreads();
  }
  hbase[t] = sh[t] - hist[t];
}

__global__ void k_place(const int* __restrict__ cnt, const int* __restrict__ hbase,
                        int* __restrict__ filld, int* __restrict__ sorted) {
  int n = blockIdx.x * blockDim.x + threadIdx.x;
  if (n >= N_NODES) return;
  int d = min(cnt[n], 127);
  sorted[hbase[d] + atomicAdd(&filld[d], 1)] = n;
}

// ---------------- W pack: gate-interleaved cols + MFMA fragment order + hi/lo ----
__global__ void k_pack(const float* __restrict__ W, unsigned short* __restrict__ Bp,
                       int K) {
  int tid = blockIdx.x * 256 + threadIdx.x;
  if (tid >= K * 64) return;
  int lane = tid & 63;
  int ntg  = (tid >> 6) & 31;
  int kb   = tid >> 11;
  int gate = ntg & 3, fg = ntg >> 2;
  int corig = gate * 128 + fg * 16 + (lane & 15);
  int k0 = kb * 32 + (lane >> 4) * 8;
  long obase = ((long)(kb * 32 + ntg) * 64 + lane) * 8;
  long plane = (long)K * 512;
  #pragma unroll
  for (int j = 0; j < 8; ++j) {
    float v = W[(long)(k0 + j) * 512 + corig];
    unsigned short h = f2bf(v);
    Bp[obase + j]         = h;
    Bp[plane + obase + j] = f2bf(v - bf2f(h));
  }
}

// ---------------- L0 body: two-pass hi/lo MFMA, 32KB-class LDS ----------------
__device__ __forceinline__ void l0_body(
    unsigned short* At, int* nodeLDS,
    const int* __restrict__ rowptr, const int2* __restrict__ eg,
    const float* __restrict__ dinv, const int* __restrict__ sorted,
    const float* __restrict__ X32, const _Float16* __restrict__ H0r,
    const unsigned short* __restrict__ Bp, const float* __restrict__ bias,
    _Float16* __restrict__ h0w, float* __restrict__ cbuf, int jidx) {
  constexpr int KB = 6;
  int tid  = threadIdx.x;
  int lane = tid & 63;
  int w    = tid >> 6;
  int b    = jidx & 7;
  int jj   = jidx >> 3;
  int g    = lane >> 4, l = lane & 15;
  int c4   = l * 4, c8 = l * 8;
  const float*    Ax = X32 + (long)b * ((long)T * N_NODES * D_INF);
  const _Float16* Bh = H0r + (long)b * N_NODES * H;
  int lane2f = 16 * (l & 3);
  int kbB    = 2 + (c8 >> 5);
  int kbA32  = c4 >> 5;
  int subA32 = (l & 7) >> 1;
  int j0A32  = (l & 1) * 4;

  bf16x8 loB_r[2];
  unsigned long long loA_r[2];

  #pragma unroll
  for (int nd = 0; nd < 2; ++nd) {
    int r  = (w << 3) + (g << 1) + nd;
    int pairIdx = jj * 32 + (r >> 1);
    int n  = (r & 1) ? sorted[N_NODES - 1 - pairIdx] : sorted[pairIdx];
    if (l == 0) nodeLDS[r] = n;
    int rs = rowptr[n], re = rowptr[n + 1];
    float accA[4] = {0.f,0.f,0.f,0.f};
    float accB[8] = {0.f,0.f,0.f,0.f,0.f,0.f,0.f,0.f};
    int e = rs;
    for (; e + 3 < re; e += 4) {
      long long m0 = *(const long long*)&eg[e + 0];
      long long m1 = *(const long long*)&eg[e + 1];
      long long m2 = *(const long long*)&eg[e + 2];
      long long m3 = *(const long long*)&eg[e + 3];
      f32x4 a0 = *(const f32x4*)(Ax + (long)(int)m0 * D_INF + c4);
      f32x4 a1 = *(const f32x4*)(Ax + (long)(int)m1 * D_INF + c4);
      f32x4 a2 = *(const f32x4*)(Ax + (long)(int)m2 * D_INF + c4);
      f32x4 a3 = *(const f32x4*)(Ax + (long)(int)m3 * D_INF + c4);
      f16x8 b0 = *(const f16x8*)(Bh + (long)(int)m0 * H + c8);
      f16x8 b1 = *(const f16x8*)(Bh + (long)(int)m1 * H + c8);
      f16x8 b2 = *(const f16x8*)(Bh + (long)(int)m2 * H + c8);
      f16x8 b3 = *(const f16x8*)(Bh + (long)(int)m3 * H + c8);
      float w0 = __int_as_float((int)(m0 >> 32)), w1 = __int_as_float((int)(m1 >> 32));
      float w2 = __int_as_float((int)(m2 >> 32)), w3 = __int_as_float((int)(m3 >> 32));
      #pragma unroll
      for (int q = 0; q < 4; ++q)
        accA[q] += w0 * a0[q] + w1 * a1[q] + w2 * a2[q] + w3 * a3[q];
      #pragma unroll
      for (int q = 0; q < 8; ++q)
        accB[q] += w0 * (float)b0[q] + w1 * (float)b1[q]
                 + w2 * (float)b2[q] + w3 * (float)b3[q];
    }
    for (; e < re; ++e) {
      long long m0 = *(const long long*)&eg[e];
      float w0 = __int_as_float((int)(m0 >> 32));
      f32x4 a0 = *(const f32x4*)(Ax + (long)(int)m0 * D_INF + c4);
      #pragma unroll
      for (int q = 0; q < 4; ++q) accA[q] += w0 * a0[q];
      f16x8 b0 = *(const f16x8*)(Bh + (long)(int)m0 * H + c8);
      #pragma unroll
      for (int q = 0; q < 8; ++q) accB[q] += w0 * (float)b0[q];
    }
    float dn = dinv[n];
    float sw = 2.0f * dn * dn;
    {
      f32x4 a = *(const f32x4*)(Ax + (long)n * D_INF + c4);
      f16x8 v = *(const f16x8*)(Bh + (long)n * H + c8);
      #pragma unroll
      for (int q = 0; q < 4; ++q) accA[q] += sw * a[q];
      #pragma unroll
      for (int q = 0; q < 8; ++q) accB[q] += sw * (float)v[q];
    }

    int mt    = r >> 4;
    int lane2 = (r & 15) + lane2f;
    {
      bf16x8 hv, lv;
      #pragma unroll
      for (int q = 0; q < 8; ++q) {
        unsigned short hs = f2bf(accB[q]);
        hv[q] = (short)hs;
        lv[q] = (short)f2bf(accB[q] - bf2f(hs));
      }
      *(bf16x8*)(At + swz((((mt) * KB + kbB) * 64 + lane2) * 8)) = hv;
      loB_r[nd] = lv;
    }
    {
      unsigned long long hv = 0ull, lv = 0ull;
      #pragma unroll
      for (int q = 0; q < 4; ++q) {
        unsigned short hs = f2bf(accA[q]);
        unsigned short ls = f2bf(accA[q] - bf2f(hs));
        hv |= (unsigned long long)hs << (16 * q);
        lv |= (unsigned long long)ls << (16 * q);
      }
      int lA = (r & 15) + 16 * subA32;
      *(unsigned long long*)(At + swz((((mt) * KB + kbA32) * 64 + lA) * 8 + j0A32)) = hv;
      loA_r[nd] = lv;
    }
  }
  __syncthreads();

  int l15 = lane & 15, lq = lane >> 4;
  const unsigned short* bb  = Bp + (long)(w * 4) * 512 + lane * 8;
  const unsigned short* blp = bb + (long)192 * 512;

  f32x4 acc[4][4];
  #pragma unroll
  for (int mt = 0; mt < 4; ++mt)
    #pragma unroll
    for (int gt = 0; gt < 4; ++gt)
      acc[mt][gt] = (f32x4){0.f, 0.f, 0.f, 0.f};

  // pass a: A-hi x (B-hi + B-lo)
  __builtin_amdgcn_s_setprio(1);
  #pragma unroll 2
  for (int kb = 0; kb < KB; ++kb) {
    bf16x8 AH_[4];
    #pragma unroll
    for (int mt = 0; mt < 4; ++mt)
      AH_[mt] = *(const bf16x8*)(At + swz((((mt) * KB + kb) * 64 + lane) * 8));
    bf16x8 BH[4], BL[4];
    #pragma unroll
    for (int gt = 0; gt < 4; ++gt) {
      BH[gt] = *(const bf16x8*)(bb  + ((long)kb * 32 + gt) * 512);
      BL[gt] = *(const bf16x8*)(blp + ((long)kb * 32 + gt) * 512);
    }
    #pragma unroll
    for (int gt = 0; gt < 4; ++gt) {
      #pragma unroll
      for (int mt = 0; mt < 4; ++mt) {
        acc[mt][gt] = __builtin_amdgcn_mfma_f32_16x16x32_bf16(AH_[mt], BH[gt], acc[mt][gt], 0, 0, 0);
        acc[mt][gt] = __builtin_amdgcn_mfma_f32_16x16x32_bf16(AH_[mt], BL[gt], acc[mt][gt], 0, 0, 0);
      }
    }
  }
  __builtin_amdgcn_s_setprio(0);
  __syncthreads();

  // overwrite LDS with lo fragments
  #pragma unroll
  for (int nd = 0; nd < 2; ++nd) {
    int r  = (w << 3) + (g << 1) + nd;
    int mt = r >> 4;
    int lane2 = (r & 15) + lane2f;
    *(bf16x8*)(At + swz((((mt) * KB + kbB) * 64 + lane2) * 8)) = loB_r[nd];
    int lA = (r & 15) + 16 * subA32;
    *(unsigned long long*)(At + swz((((mt) * KB + kbA32) * 64 + lA) * 8 + j0A32)) = loA_r[nd];
  }
  __syncthreads();

  // pass b: A-lo x B-hi
  __builtin_amdgcn_s_setprio(1);
  #pragma unroll 2
  for (int kb = 0; kb < KB; ++kb) {
    bf16x8 AL_[4];
    #pragma unroll
    for (int mt = 0; mt < 4; ++mt)
      AL_[mt] = *(const bf16x8*)(At + swz((((mt) * KB + kb) * 64 + lane) * 8));
    bf16x8 BH[4];
    #pragma unroll
    for (int gt = 0; gt < 4; ++gt)
      BH[gt] = *(const bf16x8*)(bb + ((long)kb * 32 + gt) * 512);
    #pragma unroll
    for (int gt = 0; gt < 4; ++gt)
      #pragma unroll
      for (int mt = 0; mt < 4; ++mt)
        acc[mt][gt] = __builtin_amdgcn_mfma_f32_16x16x32_bf16(AL_[mt], BH[gt], acc[mt][gt], 0, 0, 0);
  }
  __builtin_amdgcn_s_setprio(0);

  int f = w * 16 + l15;
  float bi = bias[f], bff = bias[128 + f], bo = bias[256 + f], bg = bias[384 + f];
  #pragma unroll
  for (int mt = 0; mt < 4; ++mt) {
    #pragma unroll
    for (int r = 0; r < 4; ++r) {
      int rt = mt * 16 + lq * 4 + r;
      int n2 = nodeLDS[rt];
      float vi = 1.0f / (1.0f + __expf(-(acc[mt][0][r] + bi)));
      float vf = 1.0f / (1.0f + __expf(-(acc[mt][1][r] + bff)));
      float vo = 1.0f / (1.0f + __expf(-(acc[mt][2][r] + bo)));
      float vg = tanhf(acc[mt][3][r] + bg);
      long idx = ((long)b * N_NODES + n2) * H + f;
      float cn = vf * cbuf[idx] + vi * vg;
      float hn = vo * tanhf(cn);
      cbuf[idx] = cn;
      h0w[idx] = (_Float16)hn;
    }
  }
}

// ---------------- L1 body: two-pass hi/lo MFMA, 32KB LDS ----------------
__device__ __forceinline__ void l1_body(
    unsigned short* At, int* nodeLDS,
    const int* __restrict__ rowptr, const int2* __restrict__ eg,
    const float* __restrict__ dinv, const int* __restrict__ sorted,
    const _Float16* __restrict__ H0, const _Float16* __restrict__ H1r,
    const unsigned short* __restrict__ Bp, const float* __restrict__ bias,
    _Float16* __restrict__ h1w, float* __restrict__ cbuf,
    float* __restrict__ out2, int t, int jidx) {
  constexpr int KB = 8;
  int tid  = threadIdx.x;
  int lane = tid & 63;
  int w    = tid >> 6;
  int b    = jidx & 7;
  int jj   = jidx >> 3;
  int g    = lane >> 4, l = lane & 15;
  int c8   = l * 8;
  const _Float16* A_p = H0  + (long)b * N_NODES * H;
  const _Float16* B_p = H1r + (long)b * N_NODES * H;
  int lane2f = 16 * (l & 3);
  int kbA16  = c8 >> 5;
  int kbB    = 4 + kbA16;

  bf16x8 loA_r[2], loB_r[2];

  #pragma unroll
  for (int nd = 0; nd < 2; ++nd) {
    int r  = (w << 3) + (g << 1) + nd;
    int pairIdx = jj * 32 + (r >> 1);
    int n  = (r & 1) ? sorted[N_NODES - 1 - pairIdx] : sorted[pairIdx];
    if (l == 0) nodeLDS[r] = n;
    int rs = rowptr[n], re = rowptr[n + 1];
    float accA[8] = {0.f,0.f,0.f,0.f,0.f,0.f,0.f,0.f};
    float accB[8] = {0.f,0.f,0.f,0.f,0.f,0.f,0.f,0.f};
    int e = rs;
    for (; e + 3 < re; e += 4) {
      long long m0 = *(const long long*)&eg[e + 0];
      long long m1 = *(const long long*)&eg[e + 1];
      long long m2 = *(const long long*)&eg[e + 2];
      long long m3 = *(const long long*)&eg[e + 3];
      f16x8 a0 = *(const f16x8*)(A_p + (long)(int)m0 * H + c8);
      f16x8 a1 = *(const f16x8*)(A_p + (long)(int)m1 * H + c8);
      f16x8 a2 = *(const f16x8*)(A_p + (long)(int)m2 * H + c8);
      f16x8 a3 = *(const f16x8*)(A_p + (long)(int)m3 * H + c8);
      f16x8 b0 = *(const f16x8*)(B_p + (long)(int)m0 * H + c8);
      f16x8 b1 = *(const f16x8*)(B_p + (long)(int)m1 * H + c8);
      f16x8 b2 = *(const f16x8*)(B_p + (long)(int)m2 * H + c8);
      f16x8 b3 = *(const f16x8*)(B_p + (long)(int)m3 * H + c8);
      float w0 = __int_as_float((int)(m0 >> 32)), w1 = __int_as_float((int)(m1 >> 32));
      float w2 = __int_as_float((int)(m2 >> 32)), w3 = __int_as_float((int)(m3 >> 32));
      #pragma unroll
      for (int q = 0; q < 8; ++q) {
        accA[q] += w0 * (float)a0[q] + w1 * (float)a1[q]
                 + w2 * (float)a2[q] + w3 * (float)a3[q];
        accB[q] += w0 * (float)b0[q] + w1 * (float)b1[q]
                 + w2 * (float)b2[q] + w3 * (float)b3[q];
      }
    }
    for (; e < re; ++e) {
      long long m0 = *(const long long*)&eg[e];
      float w0 = __int_as_float((int)(m0 >> 32));
      f16x8 a0 = *(const f16x8*)(A_p + (long)(int)m0 * H + c8);
      #pragma unroll
      for (int q = 0; q < 8; ++q) accA[q] += w0 * (float)a0[q];
      f16x8 b0 = *(const f16x8*)(B_p + (long)(int)m0 * H + c8);
      #pragma unroll
      for (int q = 0; q < 8; ++q) accB[q] += w0 * (float)b0[q];
    }
    float dn = dinv[n];
    float sw = 2.0f * dn * dn;
    {
      f16x8 a = *(const f16x8*)(A_p + (long)n * H + c8);
      f16x8 v = *(const f16x8*)(B_p + (long)n * H + c8);
      #pragma unroll
      for (int q = 0; q < 8; ++q) {
        accA[q] += sw * (float)a[q];
        accB[q] += sw * (float)v[q];
      }
    }

    int mt    = r >> 4;
    int lane2 = (r & 15) + lane2f;
    {
      bf16x8 hv, lv;
      #pragma unroll
      for (int q = 0; q < 8; ++q) {
        unsigned short hs = f2bf(accB[q]);
        hv[q] = (short)hs;
        lv[q] = (short)f2bf(accB[q] - bf2f(hs));
      }
      *(bf16x8*)(At + swz((((mt) * KB + kbB) * 64 + lane2) * 8)) = hv;
      loB_r[nd] = lv;
    }
    {
      bf16x8 hv, lv;
      #pragma unroll
      for (int q = 0; q < 8; ++q) {
        unsigned short hs = f2bf(accA[q]);
        hv[q] = (short)hs;
        lv[q] = (short)f2bf(accA[q] - bf2f(hs));
      }
      *(bf16x8*)(At + swz((((mt) * KB + kbA16) * 64 + lane2) * 8)) = hv;
      loA_r[nd] = lv;
    }
  }
  __syncthreads();

  int l15 = lane & 15, lq = lane >> 4;
  const unsigned short* bb  = Bp + (long)(w * 4) * 512 + lane * 8;
  const unsigned short* blp = bb + (long)256 * 512;

  f32x4 acc[4][4];
  #pragma unroll
  for (int mt = 0; mt < 4; ++mt)
    #pragma unroll
    for (int gt = 0; gt < 4; ++gt)
      acc[mt][gt] = (f32x4){0.f, 0.f, 0.f, 0.f};

  // pass a: A-hi x (B-hi + B-lo)
  __builtin_amdgcn_s_setprio(1);
  #pragma unroll 2
  for (int kb = 0; kb < KB; ++kb) {
    bf16x8 AH_[4];
    #pragma unroll
    for (int mt = 0; mt < 4; ++mt)
      AH_[mt] = *(const bf16x8*)(At + swz((((mt) * KB + kb) * 64 + lane) * 8));
    bf16x8 BH[4], BL[4];
    #pragma unroll
    for (int gt = 0; gt < 4; ++gt) {
      BH[gt] = *(const bf16x8*)(bb  + ((long)kb * 32 + gt) * 512);
      BL[gt] = *(const bf16x8*)(blp + ((long)kb * 32 + gt) * 512);
    }
    #pragma unroll
    for (int gt = 0; gt < 4; ++gt) {
      #pragma unroll
      for (int mt = 0; mt < 4; ++mt) {
        acc[mt][gt] = __builtin_amdgcn_mfma_f32_16x16x32_bf16(AH_[mt], BH[gt], acc[mt][gt], 0, 0, 0);
        acc[mt][gt] = __builtin_amdgcn_mfma_f32_16x16x32_bf16(AH_[mt], BL[gt], acc[mt][gt], 0, 0, 0);
      }
    }
  }
  __builtin_amdgcn_s_setprio(0);
  __syncthreads();

  // overwrite LDS with lo fragments
  #pragma unroll
  for (int nd = 0; nd < 2; ++nd) {
    int r  = (w << 3) + (g << 1) + nd;
    int mt = r >> 4;
    int lane2 = (r & 15) + lane2f;
    *(bf16x8*)(At + swz((((mt) * KB + kbB) * 64 + lane2) * 8)) = loB_r[nd];
    *(bf16x8*)(At + swz((((mt) * KB + kbA16) * 64 + lane2) * 8)) = loA_r[nd];
  }
  __syncthreads();

  // pass b: A-lo x B-hi
  __builtin_amdgcn_s_setprio(1);
  #pragma unroll 2
  for (int kb = 0; kb < KB; ++kb) {
    bf16x8 AL_[4];
    #pragma unroll
    for (int mt = 0; mt < 4; ++mt)
      AL_[mt] = *(const bf16x8*)(At + swz((((mt) * KB + kb) * 64 + lane) * 8));
    bf16x8 BH[4];
    #pragma unroll
    for (int gt = 0; gt < 4; ++gt)
      BH[gt] = *(const bf16x8*)(bb + ((long)kb * 32 + gt) * 512);
    #pragma unroll
    for (int gt = 0; gt < 4; ++gt)
      #pragma unroll
      for (int mt = 0; mt < 4; ++mt)
        acc[mt][gt] = __builtin_amdgcn_mfma_f32_16x16x32_bf16(AL_[mt], BH[gt], acc[mt][gt], 0, 0, 0);
  }
  __builtin_amdgcn_s_setprio(0);

  int f = w * 16 + l15;
  float bi = bias[f], bff = bias[128 + f], bo = bias[256 + f], bg = bias[384 + f];
  #pragma unroll
  for (int mt = 0; mt < 4; ++mt) {
    #pragma unroll
    for (int r = 0; r < 4; ++r) {
      int rt = mt * 16 + lq * 4 + r;
      int n2 = nodeLDS[rt];
      float vi = 1.0f / (1.0f + __expf(-(acc[mt][0][r] + bi)));
      float vf = 1.0f / (1.0f + __expf(-(acc[mt][1][r] + bff)));
      float vo = 1.0f / (1.0f + __expf(-(acc[mt][2][r] + bo)));
      float vg = tanhf(acc[mt][3][r] + bg);
      long idx = ((long)b * N_NODES + n2) * H + f;
      float cn = vf * cbuf[idx] + vi * vg;
      float hn = vo * tanhf(cn);
      cbuf[idx] = cn;
      h1w[idx] = (_Float16)hn;
      __builtin_nontemporal_store(hn,
          &out2[(((long)b * T + t) * N_NODES + n2) * H + f]);
    }
  }
}

// ---------------- k_step: MODE 0 = L1 only; 1 = L0 only; 2 = merged L1@t||L0@t+1
template<int MODE>
__global__ __launch_bounds__(512, 6) void k_step(
    const int* __restrict__ rowptr, const int2* __restrict__ eg,
    const float* __restrict__ dinv, const int* __restrict__ sorted,
    const float* __restrict__ Xt1,
    const _Float16* __restrict__ h0read,
    _Float16* __restrict__ h0write,
    const _Float16* __restrict__ h1read,
    _Float16* __restrict__ h1write,
    const unsigned short* __restrict__ Bp0, const float* __restrict__ b0,
    const unsigned short* __restrict__ Bp1, const float* __restrict__ b1,
    float* __restrict__ c0, float* __restrict__ c1,
    float* __restrict__ out2, int t) {
  __shared__ __align__(16) unsigned short At[4 * 8 * 64 * 8];  // 32 KB (hi OR lo)
  __shared__ int nodeLDS[64];
  int j = blockIdx.x;
  int role, jidx;
  if constexpr (MODE == 2) {
    role = (j >> 3) & 1;                      // alternate every 8 blocks (per-XCD mix)
    jidx = ((j >> 4) << 3) | (j & 7);
  } else {
    role = (MODE == 0) ? 0 : 1;
    jidx = j;
  }
  if (role == 0)
    l1_body(At, nodeLDS, rowptr, eg, dinv, sorted, h0read, h1read,
            Bp1, b1, h1write, c1, out2, t, jidx);
  else
    l0_body(At, nodeLDS, rowptr, eg, dinv, sorted, Xt1, h0read,
            Bp0, b0, h0write, c0, jidx);
}

// ---------------- launch ----------------

extern "C" void kernel_launch(void* const* d_in, const int* in_sizes, int n_in,
                              void* d_out, int out_size, void* d_ws, size_t ws_size,
                              hipStream_t stream) {
  const float* x  = (const float*)d_in[0];
  const float* W0 = (const float*)d_in[1];
  const float* b0 = (const float*)d_in[2];
  const float* W1 = (const float*)d_in[3];
  const float* b1 = (const float*)d_in[4];
  const int*   ei = (const int*)d_in[5];
  const int* srcp = ei;
  const int* dstp = ei + N_EDGES;
  float* out = (float*)d_out;

  char* p = (char*)d_ws;
  auto alloc = [&](size_t bytes) {
    char* r = p;
    p += (bytes + 255) & ~(size_t)255;
    return r;
  };
  int*   cnt    = (int*)  alloc(N_NODES * 4);
  int*   fill   = (int*)  alloc(N_NODES * 4);
  float* dinv   = (float*)alloc(N_NODES * 4);
  int*   rowptr = (int*)  alloc((N_NODES + 1) * 4);
  int2*  eg     = (int2*) alloc((size_t)N_EDGES * 8);
  int*   hist   = (int*)  alloc(128 * 4);
  int*   hbase  = (int*)  alloc(128 * 4);
  int*   filld  = (int*)  alloc(128 * 4);
  int*   sorted = (int*)  alloc(N_NODES * 4);
  float* cc     = (float*)alloc((size_t)2 * M * H * 4);        // c0,c1 fp32
  _Float16* hh  = (_Float16*)alloc((size_t)4 * M * H * 2);     // h0 x2, h1 x2
  unsigned short* Bp0 = (unsigned short*)alloc((size_t)192 * 512 * 2 * 2);
  unsigned short* Bp1 = (unsigned short*)alloc((size_t)256 * 512 * 2 * 2);
  float*    c0  = cc;
  float*    c1  = cc + (size_t)M * H;
  _Float16* h0a = hh;
  _Float16* h0b = hh + (size_t)M * H;
  _Float16* h1a = hh + (size_t)2 * M * H;
  _Float16* h1b = hh + (size_t)3 * M * H;

  hipMemsetAsync(cnt,   0, N_NODES * 4, stream);
  hipMemsetAsync(fill,  0, N_NODES * 4, stream);
  hipMemsetAsync(hist,  0, 128 * 4, stream);
  hipMemsetAsync(filld, 0, 128 * 4, stream);
  hipMemsetAsync(cc,    0, (size_t)2 * M * H * 4, stream);
  hipMemsetAsync(hh,    0, (size_t)4 * M * H * 2, stream);

  k_count<<<N_EDGES / 256, 256, 0, stream>>>(dstp, cnt);
  k_dinv <<<N_NODES / 256, 256, 0, stream>>>(cnt, dinv);
  k_scan <<<1, 1024, 0, stream>>>(cnt, rowptr);
  k_fill <<<N_EDGES / 256, 256, 0, stream>>>(srcp, dstp, dinv, rowptr, fill, eg);
  k_hist <<<N_NODES / 256, 256, 0, stream>>>(cnt, hist);
  k_hscan<<<1, 128, 0, stream>>>(hist, hbase);
  k_place<<<N_NODES / 256, 256, 0, stream>>>(cnt, hbase, filld, sorted);
  k_pack <<<(192 * 64 + 255) / 256, 256, 0, stream>>>(W0, Bp0, 192);
  k_pack <<<(256 * 64 + 255) / 256, 256, 0, stream>>>(W1, Bp1, 256);

  auto h0buf = [&](int tt) { return (tt & 1) ? h0b : h0a; };
  auto h1buf = [&](int tt) { return (tt & 1) ? h1b : h1a; };

  // L0@0: reads h0(-1)=h0b (zeros), writes h0(0)=h0a
  k_step<1><<<512, 512, 0, stream>>>(rowptr, eg, dinv, sorted,
      x, h0buf(-1), h0buf(0), nullptr, nullptr,
      Bp0, b0, Bp1, b1, c0, c1, nullptr, 0);

  // merged: L1@t || L0@t+1  (both read h0(t); writes disjoint)
  for (int t = 0; t < T - 1; ++t) {
    k_step<2><<<1024, 512, 0, stream>>>(rowptr, eg, dinv, sorted,
        x + (size_t)(t + 1) * N_NODES * D_INF,
        h0buf(t), h0buf(t + 1), h1buf(t - 1), h1buf(t),
        Bp0, b0, Bp1, b1, c0, c1, out, t);
  }

  // L1@7: reads h0(7), h1(6); writes h1(7), out
  k_step<0><<<512, 512, 0, stream>>>(rowptr, eg, dinv, sorted,
      nullptr, h0buf(T - 1), nullptr, h1buf(T - 2), h1buf(T - 1),
      Bp0, b0, Bp1, b1, c0, c1, out, T - 1);
}

// Round 20
// 715.841 us; speedup vs baseline: 6.7150x; 6.7150x over previous
//
#include <hip/hip_runtime.h>
#include <hip/hip_fp16.h>
#include <math.h>

constexpr int N_NODES = 4096;
constexpr int N_EDGES = 65536;
constexpr int D_INF   = 64;
constexpr int H       = 128;
constexpr int T       = 8;
constexpr int B       = 8;
constexpr int M       = B * N_NODES;

typedef __attribute__((ext_vector_type(8))) short bf16x8;
typedef __attribute__((ext_vector_type(4))) float f32x4;
typedef __attribute__((ext_vector_type(8))) _Float16 f16x8;

__device__ inline unsigned short f2bf(float x) {
  unsigned int u = __float_as_uint(x);
  unsigned int r = (u + 0x7fffu + ((u >> 16) & 1u)) >> 16;
  return (unsigned short)r;
}
__device__ inline float bf2f(unsigned short b) {
  return __uint_as_float((unsigned int)b << 16);
}
// LDS bank swizzle: XOR short-index bits 7-9 into bits 3-5 (bank bits).
__device__ __forceinline__ int swz(int s) { return s ^ (((s >> 7) & 7) << 3); }

// ---------------- CSR build ----------------

__global__ void k_count(const int* __restrict__ dst, int* __restrict__ cnt) {
  int e = blockIdx.x * blockDim.x + threadIdx.x;
  if (e < N_EDGES) atomicAdd(&cnt[dst[e]], 1);
}

__global__ void k_dinv(const int* __restrict__ cnt, float* __restrict__ dinv) {
  int n = blockIdx.x * blockDim.x + threadIdx.x;
  if (n < N_NODES) dinv[n] = 1.0f / sqrtf((float)cnt[n] + 2.0f);
}

__global__ void k_scan(const int* __restrict__ cnt, int* __restrict__ rowptr) {
  __shared__ int sums[1024];
  int t = threadIdx.x;
  int v0 = cnt[4*t+0], v1 = cnt[4*t+1], v2 = cnt[4*t+2], v3 = cnt[4*t+3];
  int s0 = v0, s1 = s0 + v1, s2 = s1 + v2, s3 = s2 + v3;
  sums[t] = s3;
  __syncthreads();
  for (int off = 1; off < 1024; off <<= 1) {
    int x = (t >= off) ? sums[t - off] : 0;
    __syncthreads();
    sums[t] += x;
    __syncthreads();
  }
  int base = (t > 0) ? sums[t - 1] : 0;
  if (t == 0) rowptr[0] = 0;
  rowptr[4*t+1] = base + s0;
  rowptr[4*t+2] = base + s1;
  rowptr[4*t+3] = base + s2;
  rowptr[4*t+4] = base + s3;
}

__global__ void k_fill(const int* __restrict__ src, const int* __restrict__ dst,
                       const float* __restrict__ dinv, const int* __restrict__ rowptr,
                       int* __restrict__ fill, int2* __restrict__ eg) {
  int e = blockIdx.x * blockDim.x + threadIdx.x;
  if (e >= N_EDGES) return;
  int s = src[e], d = dst[e];
  int p = rowptr[d] + atomicAdd(&fill[d], 1);
  eg[p] = make_int2(s, __float_as_int(dinv[s] * dinv[d]));
}

// ---- degree counting sort (work balance only; output unchanged) ----
__global__ void k_hist(const int* __restrict__ cnt, int* __restrict__ hist) {
  int n = blockIdx.x * blockDim.x + threadIdx.x;
  if (n < N_NODES) atomicAdd(&hist[min(cnt[n], 127)], 1);
}

__global__ void k_hscan(const int* __restrict__ hist, int* __restrict__ hbase) {
  __shared__ int sh[128];
  int t = threadIdx.x;
  sh[t] = hist[t];
  __syncthreads();
  for (int off = 1; off < 128; off <<= 1) {
    int x = (t >= off) ? sh[t - off] : 0;
    __syncthreads();
    sh[t] += x;
    __syncthreads();
  }
  hbase[t] = sh[t] - hist[t];
}

__global__ void k_place(const int* __restrict__ cnt, const int* __restrict__ hbase,
                        int* __restrict__ filld, int* __restrict__ sorted) {
  int n = blockIdx.x * blockDim.x + threadIdx.x;
  if (n >= N_NODES) return;
  int d = min(cnt[n], 127);
  sorted[hbase[d] + atomicAdd(&filld[d], 1)] = n;
}

// ---------------- W pack: gate-interleaved cols + MFMA fragment order + hi/lo ----
__global__ void k_pack(const float* __restrict__ W, unsigned short* __restrict__ Bp,
                       int K) {
  int tid = blockIdx.x * 256 + threadIdx.x;
  if (tid >= K * 64) return;
  int lane = tid & 63;
  int ntg  = (tid >> 6) & 31;
  int kb   = tid >> 11;
  int gate = ntg & 3, fg = ntg >> 2;
  int corig = gate * 128 + fg * 16 + (lane & 15);
  int k0 = kb * 32 + (lane >> 4) * 8;
  long obase = ((long)(kb * 32 + ntg) * 64 + lane) * 8;
  long plane = (long)K * 512;
  #pragma unroll
  for (int j = 0; j < 8; ++j) {
    float v = W[(long)(k0 + j) * 512 + corig];
    unsigned short h = f2bf(v);
    Bp[obase + j]         = h;
    Bp[plane + obase + j] = f2bf(v - bf2f(h));
  }
}

// ---------------- L0 body: gather [x | h0_old] -> LDS -> K=192 MFMA -> h0,c0 ----
__device__ __forceinline__ void l0_body(
    unsigned short* At, int* nodeLDS,
    const int* __restrict__ rowptr, const int2* __restrict__ eg,
    const float* __restrict__ dinv, const int* __restrict__ sorted,
    const float* __restrict__ X32, const _Float16* __restrict__ H0r,
    const unsigned short* __restrict__ Bp, const float* __restrict__ bias,
    _Float16* __restrict__ h0w, float* __restrict__ cbuf, int jidx) {
  constexpr int KB = 6;
  int tid  = threadIdx.x;
  int lane = tid & 63;
  int w    = tid >> 6;
  int b    = jidx & 7;
  int jj   = jidx >> 3;
  int g    = lane >> 4, l = lane & 15;
  int c4   = l * 4, c8 = l * 8;
  const float*    Ax = X32 + (long)b * ((long)T * N_NODES * D_INF);
  const _Float16* Bh = H0r + (long)b * N_NODES * H;
  int lane2f = 16 * (l & 3);
  int kbB    = 2 + (c8 >> 5);
  int kbA32  = c4 >> 5;
  int subA32 = (l & 7) >> 1;
  int j0A32  = (l & 1) * 4;

  #pragma unroll
  for (int nd = 0; nd < 2; ++nd) {
    int r  = (w << 3) + (g << 1) + nd;
    int pairIdx = jj * 32 + (r >> 1);
    int n  = (r & 1) ? sorted[N_NODES - 1 - pairIdx] : sorted[pairIdx];
    if (l == 0) nodeLDS[r] = n;
    int rs = rowptr[n], re = rowptr[n + 1];
    float accA[4] = {0.f,0.f,0.f,0.f};
    float accB[8] = {0.f,0.f,0.f,0.f,0.f,0.f,0.f,0.f};
    int e = rs;
    // 8-edge software pipeline: 16 concurrent gathers
    for (; e + 7 < re; e += 8) {
      long long m0 = *(const long long*)&eg[e + 0];
      long long m1 = *(const long long*)&eg[e + 1];
      long long m2 = *(const long long*)&eg[e + 2];
      long long m3 = *(const long long*)&eg[e + 3];
      long long m4 = *(const long long*)&eg[e + 4];
      long long m5 = *(const long long*)&eg[e + 5];
      long long m6 = *(const long long*)&eg[e + 6];
      long long m7 = *(const long long*)&eg[e + 7];
      f32x4 a0 = *(const f32x4*)(Ax + (long)(int)m0 * D_INF + c4);
      f32x4 a1 = *(const f32x4*)(Ax + (long)(int)m1 * D_INF + c4);
      f32x4 a2 = *(const f32x4*)(Ax + (long)(int)m2 * D_INF + c4);
      f32x4 a3 = *(const f32x4*)(Ax + (long)(int)m3 * D_INF + c4);
      f32x4 a4 = *(const f32x4*)(Ax + (long)(int)m4 * D_INF + c4);
      f32x4 a5 = *(const f32x4*)(Ax + (long)(int)m5 * D_INF + c4);
      f32x4 a6 = *(const f32x4*)(Ax + (long)(int)m6 * D_INF + c4);
      f32x4 a7 = *(const f32x4*)(Ax + (long)(int)m7 * D_INF + c4);
      f16x8 b0 = *(const f16x8*)(Bh + (long)(int)m0 * H + c8);
      f16x8 b1 = *(const f16x8*)(Bh + (long)(int)m1 * H + c8);
      f16x8 b2 = *(const f16x8*)(Bh + (long)(int)m2 * H + c8);
      f16x8 b3 = *(const f16x8*)(Bh + (long)(int)m3 * H + c8);
      f16x8 b4 = *(const f16x8*)(Bh + (long)(int)m4 * H + c8);
      f16x8 b5 = *(const f16x8*)(Bh + (long)(int)m5 * H + c8);
      f16x8 b6 = *(const f16x8*)(Bh + (long)(int)m6 * H + c8);
      f16x8 b7 = *(const f16x8*)(Bh + (long)(int)m7 * H + c8);
      float w0 = __int_as_float((int)(m0 >> 32)), w1 = __int_as_float((int)(m1 >> 32));
      float w2 = __int_as_float((int)(m2 >> 32)), w3 = __int_as_float((int)(m3 >> 32));
      float w4 = __int_as_float((int)(m4 >> 32)), w5 = __int_as_float((int)(m5 >> 32));
      float w6 = __int_as_float((int)(m6 >> 32)), w7 = __int_as_float((int)(m7 >> 32));
      #pragma unroll
      for (int q = 0; q < 4; ++q)
        accA[q] += (w0 * a0[q] + w1 * a1[q] + w2 * a2[q] + w3 * a3[q])
                 + (w4 * a4[q] + w5 * a5[q] + w6 * a6[q] + w7 * a7[q]);
      #pragma unroll
      for (int q = 0; q < 8; ++q)
        accB[q] += (w0 * (float)b0[q] + w1 * (float)b1[q] + w2 * (float)b2[q] + w3 * (float)b3[q])
                 + (w4 * (float)b4[q] + w5 * (float)b5[q] + w6 * (float)b6[q] + w7 * (float)b7[q]);
    }
    for (; e + 3 < re; e += 4) {
      long long m0 = *(const long long*)&eg[e + 0];
      long long m1 = *(const long long*)&eg[e + 1];
      long long m2 = *(const long long*)&eg[e + 2];
      long long m3 = *(const long long*)&eg[e + 3];
      f32x4 a0 = *(const f32x4*)(Ax + (long)(int)m0 * D_INF + c4);
      f32x4 a1 = *(const f32x4*)(Ax + (long)(int)m1 * D_INF + c4);
      f32x4 a2 = *(const f32x4*)(Ax + (long)(int)m2 * D_INF + c4);
      f32x4 a3 = *(const f32x4*)(Ax + (long)(int)m3 * D_INF + c4);
      f16x8 b0 = *(const f16x8*)(Bh + (long)(int)m0 * H + c8);
      f16x8 b1 = *(const f16x8*)(Bh + (long)(int)m1 * H + c8);
      f16x8 b2 = *(const f16x8*)(Bh + (long)(int)m2 * H + c8);
      f16x8 b3 = *(const f16x8*)(Bh + (long)(int)m3 * H + c8);
      float w0 = __int_as_float((int)(m0 >> 32)), w1 = __int_as_float((int)(m1 >> 32));
      float w2 = __int_as_float((int)(m2 >> 32)), w3 = __int_as_float((int)(m3 >> 32));
      #pragma unroll
      for (int q = 0; q < 4; ++q)
        accA[q] += w0 * a0[q] + w1 * a1[q] + w2 * a2[q] + w3 * a3[q];
      #pragma unroll
      for (int q = 0; q < 8; ++q)
        accB[q] += w0 * (float)b0[q] + w1 * (float)b1[q]
                 + w2 * (float)b2[q] + w3 * (float)b3[q];
    }
    for (; e < re; ++e) {
      long long m0 = *(const long long*)&eg[e];
      float w0 = __int_as_float((int)(m0 >> 32));
      f32x4 a0 = *(const f32x4*)(Ax + (long)(int)m0 * D_INF + c4);
      #pragma unroll
      for (int q = 0; q < 4; ++q) accA[q] += w0 * a0[q];
      f16x8 b0 = *(const f16x8*)(Bh + (long)(int)m0 * H + c8);
      #pragma unroll
      for (int q = 0; q < 8; ++q) accB[q] += w0 * (float)b0[q];
    }
    float dn = dinv[n];
    float sw = 2.0f * dn * dn;
    {
      f32x4 a = *(const f32x4*)(Ax + (long)n * D_INF + c4);
      f16x8 v = *(const f16x8*)(Bh + (long)n * H + c8);
      #pragma unroll
      for (int q = 0; q < 4; ++q) accA[q] += sw * a[q];
      #pragma unroll
      for (int q = 0; q < 8; ++q) accB[q] += sw * (float)v[q];
    }

    int mt    = r >> 4;
    int lane2 = (r & 15) + lane2f;
    {
      bf16x8 hv, lv;
      #pragma unroll
      for (int q = 0; q < 8; ++q) {
        unsigned short hs = f2bf(accB[q]);
        hv[q] = (short)hs;
        lv[q] = (short)f2bf(accB[q] - bf2f(hs));
      }
      *(bf16x8*)(At + swz((((mt)     * KB + kbB) * 64 + lane2) * 8)) = hv;
      *(bf16x8*)(At + swz((((4 + mt) * KB + kbB) * 64 + lane2) * 8)) = lv;
    }
    {
      unsigned long long hv = 0ull, lv = 0ull;
      #pragma unroll
      for (int q = 0; q < 4; ++q) {
        unsigned short hs = f2bf(accA[q]);
        unsigned short ls = f2bf(accA[q] - bf2f(hs));
        hv |= (unsigned long long)hs << (16 * q);
        lv |= (unsigned long long)ls << (16 * q);
      }
      int lA = (r & 15) + 16 * subA32;
      *(unsigned long long*)(At + swz((((mt)     * KB + kbA32) * 64 + lA) * 8 + j0A32)) = hv;
      *(unsigned long long*)(At + swz((((4 + mt) * KB + kbA32) * 64 + lA) * 8 + j0A32)) = lv;
    }
  }
  __syncthreads();

  int l15 = lane & 15, lq = lane >> 4;
  const unsigned short* bb  = Bp + (long)(w * 4) * 512 + lane * 8;
  const unsigned short* blp = bb + (long)192 * 512;

  f32x4 acc[4][4];
  #pragma unroll
  for (int mt = 0; mt < 4; ++mt)
    #pragma unroll
    for (int gt = 0; gt < 4; ++gt)
      acc[mt][gt] = (f32x4){0.f, 0.f, 0.f, 0.f};

  __builtin_amdgcn_s_setprio(1);
  #pragma unroll 2
  for (int kb = 0; kb < KB; ++kb) {
    bf16x8 AH_[4], AL_[4];
    #pragma unroll
    for (int mt = 0; mt < 4; ++mt) {
      AH_[mt] = *(const bf16x8*)(At + swz((((mt)     * KB + kb) * 64 + lane) * 8));
      AL_[mt] = *(const bf16x8*)(At + swz((((4 + mt) * KB + kb) * 64 + lane) * 8));
    }
    bf16x8 BH[4], BL[4];
    #pragma unroll
    for (int gt = 0; gt < 4; ++gt) {
      BH[gt] = *(const bf16x8*)(bb  + ((long)kb * 32 + gt) * 512);
      BL[gt] = *(const bf16x8*)(blp + ((long)kb * 32 + gt) * 512);
    }
    #pragma unroll
    for (int gt = 0; gt < 4; ++gt) {
      #pragma unroll
      for (int mt = 0; mt < 4; ++mt) {
        acc[mt][gt] = __builtin_amdgcn_mfma_f32_16x16x32_bf16(AH_[mt], BH[gt], acc[mt][gt], 0, 0, 0);
        acc[mt][gt] = __builtin_amdgcn_mfma_f32_16x16x32_bf16(AL_[mt], BH[gt], acc[mt][gt], 0, 0, 0);
        acc[mt][gt] = __builtin_amdgcn_mfma_f32_16x16x32_bf16(AH_[mt], BL[gt], acc[mt][gt], 0, 0, 0);
      }
    }
  }
  __builtin_amdgcn_s_setprio(0);

  int f = w * 16 + l15;
  float bi = bias[f], bff = bias[128 + f], bo = bias[256 + f], bg = bias[384 + f];
  #pragma unroll
  for (int mt = 0; mt < 4; ++mt) {
    #pragma unroll
    for (int r = 0; r < 4; ++r) {
      int rt = mt * 16 + lq * 4 + r;
      int n2 = nodeLDS[rt];
      float vi = 1.0f / (1.0f + __expf(-(acc[mt][0][r] + bi)));
      float vf = 1.0f / (1.0f + __expf(-(acc[mt][1][r] + bff)));
      float vo = 1.0f / (1.0f + __expf(-(acc[mt][2][r] + bo)));
      float vg = tanhf(acc[mt][3][r] + bg);
      long idx = ((long)b * N_NODES + n2) * H + f;
      float cn = vf * cbuf[idx] + vi * vg;
      float hn = vo * tanhf(cn);
      cbuf[idx] = cn;
      h0w[idx] = (_Float16)hn;
    }
  }
}

// ---------------- L1 body: gather [h0 | h1_old] -> LDS -> K=256 MFMA -> h1,c1,out
__device__ __forceinline__ void l1_body(
    unsigned short* At, int* nodeLDS,
    const int* __restrict__ rowptr, const int2* __restrict__ eg,
    const float* __restrict__ dinv, const int* __restrict__ sorted,
    const _Float16* __restrict__ H0, const _Float16* __restrict__ H1r,
    const unsigned short* __restrict__ Bp, const float* __restrict__ bias,
    _Float16* __restrict__ h1w, float* __restrict__ cbuf,
    float* __restrict__ out2, int t, int jidx) {
  constexpr int KB = 8;
  int tid  = threadIdx.x;
  int lane = tid & 63;
  int w    = tid >> 6;
  int b    = jidx & 7;
  int jj   = jidx >> 3;
  int g    = lane >> 4, l = lane & 15;
  int c8   = l * 8;
  const _Float16* A_p = H0  + (long)b * N_NODES * H;
  const _Float16* B_p = H1r + (long)b * N_NODES * H;
  int lane2f = 16 * (l & 3);
  int kbA16  = c8 >> 5;
  int kbB    = 4 + kbA16;

  #pragma unroll
  for (int nd = 0; nd < 2; ++nd) {
    int r  = (w << 3) + (g << 1) + nd;
    int pairIdx = jj * 32 + (r >> 1);
    int n  = (r & 1) ? sorted[N_NODES - 1 - pairIdx] : sorted[pairIdx];
    if (l == 0) nodeLDS[r] = n;
    int rs = rowptr[n], re = rowptr[n + 1];
    float accA[8] = {0.f,0.f,0.f,0.f,0.f,0.f,0.f,0.f};
    float accB[8] = {0.f,0.f,0.f,0.f,0.f,0.f,0.f,0.f};
    int e = rs;
    // 8-edge software pipeline: 16 concurrent gathers
    for (; e + 7 < re; e += 8) {
      long long m0 = *(const long long*)&eg[e + 0];
      long long m1 = *(const long long*)&eg[e + 1];
      long long m2 = *(const long long*)&eg[e + 2];
      long long m3 = *(const long long*)&eg[e + 3];
      long long m4 = *(const long long*)&eg[e + 4];
      long long m5 = *(const long long*)&eg[e + 5];
      long long m6 = *(const long long*)&eg[e + 6];
      long long m7 = *(const long long*)&eg[e + 7];
      f16x8 a0 = *(const f16x8*)(A_p + (long)(int)m0 * H + c8);
      f16x8 a1 = *(const f16x8*)(A_p + (long)(int)m1 * H + c8);
      f16x8 a2 = *(const f16x8*)(A_p + (long)(int)m2 * H + c8);
      f16x8 a3 = *(const f16x8*)(A_p + (long)(int)m3 * H + c8);
      f16x8 a4 = *(const f16x8*)(A_p + (long)(int)m4 * H + c8);
      f16x8 a5 = *(const f16x8*)(A_p + (long)(int)m5 * H + c8);
      f16x8 a6 = *(const f16x8*)(A_p + (long)(int)m6 * H + c8);
      f16x8 a7 = *(const f16x8*)(A_p + (long)(int)m7 * H + c8);
      f16x8 b0 = *(const f16x8*)(B_p + (long)(int)m0 * H + c8);
      f16x8 b1 = *(const f16x8*)(B_p + (long)(int)m1 * H + c8);
      f16x8 b2 = *(const f16x8*)(B_p + (long)(int)m2 * H + c8);
      f16x8 b3 = *(const f16x8*)(B_p + (long)(int)m3 * H + c8);
      f16x8 b4 = *(const f16x8*)(B_p + (long)(int)m4 * H + c8);
      f16x8 b5 = *(const f16x8*)(B_p + (long)(int)m5 * H + c8);
      f16x8 b6 = *(const f16x8*)(B_p + (long)(int)m6 * H + c8);
      f16x8 b7 = *(const f16x8*)(B_p + (long)(int)m7 * H + c8);
      float w0 = __int_as_float((int)(m0 >> 32)), w1 = __int_as_float((int)(m1 >> 32));
      float w2 = __int_as_float((int)(m2 >> 32)), w3 = __int_as_float((int)(m3 >> 32));
      float w4 = __int_as_float((int)(m4 >> 32)), w5 = __int_as_float((int)(m5 >> 32));
      float w6 = __int_as_float((int)(m6 >> 32)), w7 = __int_as_float((int)(m7 >> 32));
      #pragma unroll
      for (int q = 0; q < 8; ++q) {
        accA[q] += (w0 * (float)a0[q] + w1 * (float)a1[q] + w2 * (float)a2[q] + w3 * (float)a3[q])
                 + (w4 * (float)a4[q] + w5 * (float)a5[q] + w6 * (float)a6[q] + w7 * (float)a7[q]);
        accB[q] += (w0 * (float)b0[q] + w1 * (float)b1[q] + w2 * (float)b2[q] + w3 * (float)b3[q])
                 + (w4 * (float)b4[q] + w5 * (float)b5[q] + w6 * (float)b6[q] + w7 * (float)b7[q]);
      }
    }
    for (; e + 3 < re; e += 4) {
      long long m0 = *(const long long*)&eg[e + 0];
      long long m1 = *(const long long*)&eg[e + 1];
      long long m2 = *(const long long*)&eg[e + 2];
      long long m3 = *(const long long*)&eg[e + 3];
      f16x8 a0 = *(const f16x8*)(A_p + (long)(int)m0 * H + c8);
      f16x8 a1 = *(const f16x8*)(A_p + (long)(int)m1 * H + c8);
      f16x8 a2 = *(const f16x8*)(A_p + (long)(int)m2 * H + c8);
      f16x8 a3 = *(const f16x8*)(A_p + (long)(int)m3 * H + c8);
      f16x8 b0 = *(const f16x8*)(B_p + (long)(int)m0 * H + c8);
      f16x8 b1 = *(const f16x8*)(B_p + (long)(int)m1 * H + c8);
      f16x8 b2 = *(const f16x8*)(B_p + (long)(int)m2 * H + c8);
      f16x8 b3 = *(const f16x8*)(B_p + (long)(int)m3 * H + c8);
      float w0 = __int_as_float((int)(m0 >> 32)), w1 = __int_as_float((int)(m1 >> 32));
      float w2 = __int_as_float((int)(m2 >> 32)), w3 = __int_as_float((int)(m3 >> 32));
      #pragma unroll
      for (int q = 0; q < 8; ++q) {
        accA[q] += w0 * (float)a0[q] + w1 * (float)a1[q]
                 + w2 * (float)a2[q] + w3 * (float)a3[q];
        accB[q] += w0 * (float)b0[q] + w1 * (float)b1[q]
                 + w2 * (float)b2[q] + w3 * (float)b3[q];
      }
    }
    for (; e < re; ++e) {
      long long m0 = *(const long long*)&eg[e];
      float w0 = __int_as_float((int)(m0 >> 32));
      f16x8 a0 = *(const f16x8*)(A_p + (long)(int)m0 * H + c8);
      #pragma unroll
      for (int q = 0; q < 8; ++q) accA[q] += w0 * (float)a0[q];
      f16x8 b0 = *(const f16x8*)(B_p + (long)(int)m0 * H + c8);
      #pragma unroll
      for (int q = 0; q < 8; ++q) accB[q] += w0 * (float)b0[q];
    }
    float dn = dinv[n];
    float sw = 2.0f * dn * dn;
    {
      f16x8 a = *(const f16x8*)(A_p + (long)n * H + c8);
      f16x8 v = *(const f16x8*)(B_p + (long)n * H + c8);
      #pragma unroll
      for (int q = 0; q < 8; ++q) {
        accA[q] += sw * (float)a[q];
        accB[q] += sw * (float)v[q];
      }
    }

    int mt    = r >> 4;
    int lane2 = (r & 15) + lane2f;
    {
      bf16x8 hv, lv;
      #pragma unroll
      for (int q = 0; q < 8; ++q) {
        unsigned short hs = f2bf(accB[q]);
        hv[q] = (short)hs;
        lv[q] = (short)f2bf(accB[q] - bf2f(hs));
      }
      *(bf16x8*)(At + swz((((mt)     * KB + kbB) * 64 + lane2) * 8)) = hv;
      *(bf16x8*)(At + swz((((4 + mt) * KB + kbB) * 64 + lane2) * 8)) = lv;
    }
    {
      bf16x8 hv, lv;
      #pragma unroll
      for (int q = 0; q < 8; ++q) {
        unsigned short hs = f2bf(accA[q]);
        hv[q] = (short)hs;
        lv[q] = (short)f2bf(accA[q] - bf2f(hs));
      }
      *(bf16x8*)(At + swz((((mt)     * KB + kbA16) * 64 + lane2) * 8)) = hv;
      *(bf16x8*)(At + swz((((4 + mt) * KB + kbA16) * 64 + lane2) * 8)) = lv;
    }
  }
  __syncthreads();

  int l15 = lane & 15, lq = lane >> 4;
  const unsigned short* bb  = Bp + (long)(w * 4) * 512 + lane * 8;
  const unsigned short* blp = bb + (long)256 * 512;

  f32x4 acc[4][4];
  #pragma unroll
  for (int mt = 0; mt < 4; ++mt)
    #pragma unroll
    for (int gt = 0; gt < 4; ++gt)
      acc[mt][gt] = (f32x4){0.f, 0.f, 0.f, 0.f};

  __builtin_amdgcn_s_setprio(1);
  #pragma unroll 2
  for (int kb = 0; kb < KB; ++kb) {
    bf16x8 AH_[4], AL_[4];
    #pragma unroll
    for (int mt = 0; mt < 4; ++mt) {
      AH_[mt] = *(const bf16x8*)(At + swz((((mt)     * KB + kb) * 64 + lane) * 8));
      AL_[mt] = *(const bf16x8*)(At + swz((((4 + mt) * KB + kb) * 64 + lane) * 8));
    }
    bf16x8 BH[4], BL[4];
    #pragma unroll
    for (int gt = 0; gt < 4; ++gt) {
      BH[gt] = *(const bf16x8*)(bb  + ((long)kb * 32 + gt) * 512);
      BL[gt] = *(const bf16x8*)(blp + ((long)kb * 32 + gt) * 512);
    }
    #pragma unroll
    for (int gt = 0; gt < 4; ++gt) {
      #pragma unroll
      for (int mt = 0; mt < 4; ++mt) {
        acc[mt][gt] = __builtin_amdgcn_mfma_f32_16x16x32_bf16(AH_[mt], BH[gt], acc[mt][gt], 0, 0, 0);
        acc[mt][gt] = __builtin_amdgcn_mfma_f32_16x16x32_bf16(AL_[mt], BH[gt], acc[mt][gt], 0, 0, 0);
        acc[mt][gt] = __builtin_amdgcn_mfma_f32_16x16x32_bf16(AH_[mt], BL[gt], acc[mt][gt], 0, 0, 0);
      }
    }
  }
  __builtin_amdgcn_s_setprio(0);

  int f = w * 16 + l15;
  float bi = bias[f], bff = bias[128 + f], bo = bias[256 + f], bg = bias[384 + f];
  #pragma unroll
  for (int mt = 0; mt < 4; ++mt) {
    #pragma unroll
    for (int r = 0; r < 4; ++r) {
      int rt = mt * 16 + lq * 4 + r;
      int n2 = nodeLDS[rt];
      float vi = 1.0f / (1.0f + __expf(-(acc[mt][0][r] + bi)));
      float vf = 1.0f / (1.0f + __expf(-(acc[mt][1][r] + bff)));
      float vo = 1.0f / (1.0f + __expf(-(acc[mt][2][r] + bo)));
      float vg = tanhf(acc[mt][3][r] + bg);
      long idx = ((long)b * N_NODES + n2) * H + f;
      float cn = vf * cbuf[idx] + vi * vg;
      float hn = vo * tanhf(cn);
      cbuf[idx] = cn;
      h1w[idx] = (_Float16)hn;
      __builtin_nontemporal_store(hn,
          &out2[(((long)b * T + t) * N_NODES + n2) * H + f]);
    }
  }
}

// ---------------- k_step: MODE 0 = L1 only; 1 = L0 only; 2 = merged L1@t||L0@t+1
template<int MODE>
__global__ __launch_bounds__(512, 4) void k_step(
    const int* __restrict__ rowptr, const int2* __restrict__ eg,
    const float* __restrict__ dinv, const int* __restrict__ sorted,
    const float* __restrict__ Xt1,
    const _Float16* __restrict__ h0read,
    _Float16* __restrict__ h0write,
    const _Float16* __restrict__ h1read,
    _Float16* __restrict__ h1write,
    const unsigned short* __restrict__ Bp0, const float* __restrict__ b0,
    const unsigned short* __restrict__ Bp1, const float* __restrict__ b1,
    float* __restrict__ c0, float* __restrict__ c1,
    float* __restrict__ out2, int t) {
  __shared__ __align__(16) unsigned short At[8 * 8 * 64 * 8];  // 64 KB
  __shared__ int nodeLDS[64];
  int j = blockIdx.x;
  int role, jidx;
  if constexpr (MODE == 2) {
    role = (j >> 3) & 1;                      // alternate every 8 blocks (per-XCD mix)
    jidx = ((j >> 4) << 3) | (j & 7);
  } else {
    role = (MODE == 0) ? 0 : 1;
    jidx = j;
  }
  if (role == 0)
    l1_body(At, nodeLDS, rowptr, eg, dinv, sorted, h0read, h1read,
            Bp1, b1, h1write, c1, out2, t, jidx);
  else
    l0_body(At, nodeLDS, rowptr, eg, dinv, sorted, Xt1, h0read,
            Bp0, b0, h0write, c0, jidx);
}

// ---------------- launch ----------------

extern "C" void kernel_launch(void* const* d_in, const int* in_sizes, int n_in,
                              void* d_out, int out_size, void* d_ws, size_t ws_size,
                              hipStream_t stream) {
  const float* x  = (const float*)d_in[0];
  const float* W0 = (const float*)d_in[1];
  const float* b0 = (const float*)d_in[2];
  const float* W1 = (const float*)d_in[3];
  const float* b1 = (const float*)d_in[4];
  const int*   ei = (const int*)d_in[5];
  const int* srcp = ei;
  const int* dstp = ei + N_EDGES;
  float* out = (float*)d_out;

  char* p = (char*)d_ws;
  auto alloc = [&](size_t bytes) {
    char* r = p;
    p += (bytes + 255) & ~(size_t)255;
    return r;
  };
  int*   cnt    = (int*)  alloc(N_NODES * 4);
  int*   fill   = (int*)  alloc(N_NODES * 4);
  float* dinv   = (float*)alloc(N_NODES * 4);
  int*   rowptr = (int*)  alloc((N_NODES + 1) * 4);
  int2*  eg     = (int2*) alloc((size_t)N_EDGES * 8);
  int*   hist   = (int*)  alloc(128 * 4);
  int*   hbase  = (int*)  alloc(128 * 4);
  int*   filld  = (int*)  alloc(128 * 4);
  int*   sorted = (int*)  alloc(N_NODES * 4);
  float* cc     = (float*)alloc((size_t)2 * M * H * 4);        // c0,c1 fp32
  _Float16* hh  = (_Float16*)alloc((size_t)4 * M * H * 2);     // h0 x2, h1 x2
  unsigned short* Bp0 = (unsigned short*)alloc((size_t)192 * 512 * 2 * 2);
  unsigned short* Bp1 = (unsigned short*)alloc((size_t)256 * 512 * 2 * 2);
  float*    c0  = cc;
  float*    c1  = cc + (size_t)M * H;
  _Float16* h0a = hh;
  _Float16* h0b = hh + (size_t)M * H;
  _Float16* h1a = hh + (size_t)2 * M * H;
  _Float16* h1b = hh + (size_t)3 * M * H;

  hipMemsetAsync(cnt,   0, N_NODES * 4, stream);
  hipMemsetAsync(fill,  0, N_NODES * 4, stream);
  hipMemsetAsync(hist,  0, 128 * 4, stream);
  hipMemsetAsync(filld, 0, 128 * 4, stream);
  hipMemsetAsync(cc,    0, (size_t)2 * M * H * 4, stream);
  hipMemsetAsync(hh,    0, (size_t)4 * M * H * 2, stream);

  k_count<<<N_EDGES / 256, 256, 0, stream>>>(dstp, cnt);
  k_dinv <<<N_NODES / 256, 256, 0, stream>>>(cnt, dinv);
  k_scan <<<1, 1024, 0, stream>>>(cnt, rowptr);
  k_fill <<<N_EDGES / 256, 256, 0, stream>>>(srcp, dstp, dinv, rowptr, fill, eg);
  k_hist <<<N_NODES / 256, 256, 0, stream>>>(cnt, hist);
  k_hscan<<<1, 128, 0, stream>>>(hist, hbase);
  k_place<<<N_NODES / 256, 256, 0, stream>>>(cnt, hbase, filld, sorted);
  k_pack <<<(192 * 64 + 255) / 256, 256, 0, stream>>>(W0, Bp0, 192);
  k_pack <<<(256 * 64 + 255) / 256, 256, 0, stream>>>(W1, Bp1, 256);

  auto h0buf = [&](int tt) { return (tt & 1) ? h0b : h0a; };
  auto h1buf = [&](int tt) { return (tt & 1) ? h1b : h1a; };

  // L0@0: reads h0(-1)=h0b (zeros), writes h0(0)=h0a
  k_step<1><<<512, 512, 0, stream>>>(rowptr, eg, dinv, sorted,
      x, h0buf(-1), h0buf(0), nullptr, nullptr,
      Bp0, b0, Bp1, b1, c0, c1, nullptr, 0);

  // merged: L1@t || L0@t+1  (both read h0(t); writes disjoint)
  for (int t = 0; t < T - 1; ++t) {
    k_step<2><<<1024, 512, 0, stream>>>(rowptr, eg, dinv, sorted,
        x + (size_t)(t + 1) * N_NODES * D_INF,
        h0buf(t), h0buf(t + 1), h1buf(t - 1), h1buf(t),
        Bp0, b0, Bp1, b1, c0, c1, out, t);
  }

  // L1@7: reads h0(7), h1(6); writes h1(7), out
  k_step<0><<<512, 512, 0, stream>>>(rowptr, eg, dinv, sorted,
      nullptr, h0buf(T - 1), nullptr, h1buf(T - 2), h1buf(T - 1),
      Bp0, b0, Bp1, b1, c0, c1, out, T - 1);
}